// Round 1
// baseline (864.372 us; speedup 1.0000x reference)
//
#include <hip/hip_runtime.h>

// RVQ: per token (65536), per head (3): argmin_k ||x_h - c_hk||^2 over 16
// codewords of dim 256; out = alpha*x + (1-alpha)*c[argmin]; code = packed inds.
// Memory-bound: ~403 MB HBM traffic => ~64 us floor at 6.3 TB/s.
//
// Layout: wave (64 lanes) handles TB=4 tokens. Each head slice is 256 floats
// = exactly 64 lanes x float4 -> fully coalesced global loads/stores.
// Codebook (48 KB) staged in LDS once per block; c-row reads are contiguous
// 1KB per ds_read_b128 wave-access -> conflict-free.
// Dot products: per-lane dot4 partials, full 64-lane butterfly reduce
// (pairwise tree, good fp accuracy to match np argmin on near-ties).
// Score mimics ref rounding: (xx - 2*dot) + cn, strict < keeps first index.

#define NH 3
#define NK 16
#define DHEAD 256
#define DFULL 768
#define TB 4          // tokens per wave per iteration

__global__ __launch_bounds__(256) void rvq_kernel(
    const float* __restrict__ x,
    const float* __restrict__ cb,
    const float* __restrict__ alphap,
    float* __restrict__ out,
    float* __restrict__ code,
    int n_tokens, int n_waves)
{
    __shared__ float lcb[NH * NK * DHEAD];   // 48 KB codebook
    __shared__ float lcn[NH * NK];           // codeword squared norms

    const int tid = threadIdx.x;

    // ---- stage codebook into LDS (coalesced float4) ----
    const float4* cb4 = (const float4*)cb;
    float4* lcb4 = (float4*)lcb;
    #pragma unroll
    for (int i = tid; i < NH * NK * DHEAD / 4; i += 256) lcb4[i] = cb4[i];

    // ---- codeword norms: entry e = tid>>2 (0..47), quarter q = tid&3 ----
    if (tid < NH * NK * 4) {
        const int e = tid >> 2, q = tid & 3;
        const float4* cp = cb4 + e * (DHEAD / 4) + q * (DHEAD / 16);
        float s = 0.f;
        #pragma unroll
        for (int i = 0; i < DHEAD / 16; ++i) {
            float4 c = cp[i];
            s += c.x * c.x + c.y * c.y + c.z * c.z + c.w * c.w;
        }
        s += __shfl_xor(s, 1);
        s += __shfl_xor(s, 2);
        if (q == 0) lcn[e] = s;
    }
    __syncthreads();

    const float alpha = alphap[0];
    const float beta  = 1.0f - alpha;
    const int lane = tid & 63;
    const int wid  = (blockIdx.x << 2) | (tid >> 6);   // block = 4 waves

    // n_tokens (65536) is divisible by TB; strides keep t0+TB <= n_tokens.
    for (int t0 = wid * TB; t0 < n_tokens; t0 += n_waves * TB) {
        // load x fragments: lane holds 4 floats of each (token, head) slice
        float4 xf[TB][NH];
        #pragma unroll
        for (int t = 0; t < TB; ++t) {
            const float4* xt = (const float4*)(x + (size_t)(t0 + t) * DFULL);
            #pragma unroll
            for (int h = 0; h < NH; ++h)
                xf[t][h] = xt[h * 64 + lane];
        }

        int ind[TB][NH];
        #pragma unroll
        for (int h = 0; h < NH; ++h) {
            const float4* ch = (const float4*)(lcb + h * NK * DHEAD);
            float part[TB][NK];
            float xx[TB];
            #pragma unroll
            for (int t = 0; t < TB; ++t) {
                xx[t] = xf[t][h].x * xf[t][h].x + xf[t][h].y * xf[t][h].y
                      + xf[t][h].z * xf[t][h].z + xf[t][h].w * xf[t][h].w;
            }
            #pragma unroll
            for (int k = 0; k < NK; ++k) {
                float4 c = ch[k * 64 + lane];       // contiguous 1KB wave read
                #pragma unroll
                for (int t = 0; t < TB; ++t) {
                    part[t][k] = xf[t][h].x * c.x + xf[t][h].y * c.y
                               + xf[t][h].z * c.z + xf[t][h].w * c.w;
                }
            }
            // 64-lane butterfly reduce: all lanes end with full sums
            #pragma unroll
            for (int s = 1; s < 64; s <<= 1) {
                #pragma unroll
                for (int t = 0; t < TB; ++t) {
                    xx[t] += __shfl_xor(xx[t], s);
                    #pragma unroll
                    for (int k = 0; k < NK; ++k)
                        part[t][k] += __shfl_xor(part[t][k], s);
                }
            }
            #pragma unroll
            for (int t = 0; t < TB; ++t) {
                // score = (xx - 2*dot) + cn, same rounding structure as ref
                float best = (xx[t] - 2.0f * part[t][0]) + lcn[h * NK];
                int bi = 0;
                #pragma unroll
                for (int k = 1; k < NK; ++k) {
                    float sc = (xx[t] - 2.0f * part[t][k]) + lcn[h * NK + k];
                    if (sc < best) { best = sc; bi = k; }   // strict <: first idx wins
                }
                ind[t][h] = bi;
                float4 c = ch[bi * 64 + lane];
                float4 o;
                o.x = alpha * xf[t][h].x + beta * c.x;
                o.y = alpha * xf[t][h].y + beta * c.y;
                o.z = alpha * xf[t][h].z + beta * c.z;
                o.w = alpha * xf[t][h].w + beta * c.w;
                ((float4*)(out + (size_t)(t0 + t) * DFULL))[h * 64 + lane] = o;
            }
        }
        if (lane == 0) {
            #pragma unroll
            for (int t = 0; t < TB; ++t) {
                // code written as float (d_out is read back as float32)
                code[t0 + t] = (float)(ind[t][0] + NK * ind[t][1]
                                       + NK * NK * ind[t][2]);
            }
        }
    }
}

extern "C" void kernel_launch(void* const* d_in, const int* in_sizes, int n_in,
                              void* d_out, int out_size, void* d_ws, size_t ws_size,
                              hipStream_t stream) {
    const float* x      = (const float*)d_in[0];
    const float* cb     = (const float*)d_in[1];
    const float* alphap = (const float*)d_in[2];
    const int n_tokens = in_sizes[0] / DFULL;           // 65536
    float* out  = (float*)d_out;
    float* code = out + (size_t)n_tokens * DFULL;       // second output, flat-concat

    const int grid = 1024;                               // 4 waves/block
    const int n_waves = grid * 4;
    rvq_kernel<<<grid, 256, 0, stream>>>(x, cb, alphap, out, code,
                                         n_tokens, n_waves);
}

// Round 2
// 360.619 us; speedup vs baseline: 2.3969x; 2.3969x over previous
//
#include <hip/hip_runtime.h>

// RVQ round 2. Per head (blockIdx.y): argmin_k(|c_k|^2 - 2<x,c_k>) over 16
// codewords (|x|^2 dropped - constant in k), blend + atomic code pack.
//
// Key structure: lane l "owns" codeword k=h(l); partial-dot vector v[j] holds
// k = j ^ h(l). Recursive-halving xor reduce-scatter: 16 values -> 1 in
// 15 exchanges (8x xor2 + 4x xor1 on DPP/VALU pipe, 2x xor4 + 1x xor8 on
// ds_swizzle) + 2 full-sum steps (xor16, xor32). h(l) chosen so the two
// DPP-able distances carry the largest exchange counts:
//   h(l) = bit1(l)<<3 | bit0(l)<<2 | bit2(l)<<1 | bit3(l)
// consistency: h(l^2)=h^8, h(l^1)=h^4, h(l^4)=h^2, h(l^8)=h^1.
// Argmin: 4 min-steps over k-owner bits (xor1,2 DPP; xor4,8 swizzle), then
// ballot(sc==m) + ctz -> wave-uniform best k. No index shuffles.

#define NH 3
#define NK 16
#define DHEAD 256
#define DFULL 768
#define TB 4

typedef float f2 __attribute__((ext_vector_type(2)));

__device__ __forceinline__ float dpp_xor1(float x) {
    return __builtin_bit_cast(float, __builtin_amdgcn_mov_dpp(
        __builtin_bit_cast(int, x), 0xB1, 0xF, 0xF, false));  // quad_perm(1,0,3,2)
}
__device__ __forceinline__ float dpp_xor2(float x) {
    return __builtin_bit_cast(float, __builtin_amdgcn_mov_dpp(
        __builtin_bit_cast(int, x), 0x4E, 0xF, 0xF, false));  // quad_perm(2,3,0,1)
}
__device__ __forceinline__ float swz_xor4(float x) {
    return __builtin_bit_cast(float, __builtin_amdgcn_ds_swizzle(
        __builtin_bit_cast(int, x), 0x101F));
}
__device__ __forceinline__ float swz_xor8(float x) {
    return __builtin_bit_cast(float, __builtin_amdgcn_ds_swizzle(
        __builtin_bit_cast(int, x), 0x201F));
}
__device__ __forceinline__ float swz_xor16(float x) {
    return __builtin_bit_cast(float, __builtin_amdgcn_ds_swizzle(
        __builtin_bit_cast(int, x), 0x401F));
}

__global__ __launch_bounds__(256, 4) void rvq_head_kernel(
    const float* __restrict__ x,
    const float* __restrict__ cb,
    const float* __restrict__ alphap,
    float* __restrict__ out,
    float* __restrict__ codef,
    int tok_per_block)
{
    const int h = blockIdx.y;
    __shared__ float lc[NK * DHEAD];     // 16 KB codebook, head h, stride 256
    __shared__ float lps[NK * 16];       // norm partials
    __shared__ float lcn[NK];            // codeword squared norms

    const int tid = threadIdx.x;

    // stage head-h codebook (coalesced float4)
    const float4* cb4 = (const float4*)(cb + (size_t)h * NK * DHEAD);
    float4* lc4w = (float4*)lc;
    #pragma unroll
    for (int i = 0; i < 4; ++i) lc4w[tid + i * 256] = cb4[tid + i * 256];

    // codeword norm partials: thread i -> row i>>4, 16 dims at (i&15)*16
    {
        const int r = tid >> 4, dd = (tid & 15) * 16;
        const float4* p = (const float4*)(cb + (size_t)h * NK * DHEAD + r * DHEAD + dd);
        float s = 0.f;
        #pragma unroll
        for (int q = 0; q < 4; ++q) {
            float4 c = p[q];
            s += c.x * c.x + c.y * c.y + c.z * c.z + c.w * c.w;
        }
        lps[tid] = s;
    }
    __syncthreads();
    if (tid < NK) {
        float s = 0.f;
        #pragma unroll
        for (int q = 0; q < 16; ++q) s += lps[tid * 16 + q];
        lcn[tid] = s;
    }
    __syncthreads();

    const int lane = tid & 63;
    const int wid  = tid >> 6;
    // k owned by this lane after reduce-scatter
    const int hl = (((lane >> 1) & 1) << 3) | ((lane & 1) << 2)
                 | (((lane >> 2) & 1) << 1) | ((lane >> 3) & 1);
    const float cn_l  = lcn[hl];
    const float alpha = alphap[0];
    const float beta  = 1.0f - alpha;
    const float kscale = (float)(1 << (4 * h));

    const float4* x4   = (const float4*)x;
    float4* out4       = (float4*)out;
    const float4* lc4  = (const float4*)lc;

    const int t_base = blockIdx.x * tok_per_block;
    const int t_end  = t_base + tok_per_block;

    for (int t0 = t_base + wid * TB; t0 < t_end; t0 += 4 * TB) {
        float4 xf[TB];
        #pragma unroll
        for (int t = 0; t < TB; ++t)
            xf[t] = x4[(size_t)(t0 + t) * (DFULL / 4) + h * 64 + lane];

        // partial dots: v[t][j] = <x4_lane, c[j^hl]_lane> (packed fp32 fma)
        float v[TB][NK];
        #pragma unroll
        for (int j = 0; j < NK; ++j) {
            float4 c = lc4[((j ^ hl) << 6) | lane];
            #pragma unroll
            for (int t = 0; t < TB; ++t) {
                f2 p = (f2){xf[t].x, xf[t].y} * (f2){c.x, c.y};
                p += (f2){xf[t].z, xf[t].w} * (f2){c.z, c.w};
                v[t][j] = p.x + p.y;
            }
        }

        // recursive-halving reduce-scatter + full sum
        #pragma unroll
        for (int t = 0; t < TB; ++t) {
            #pragma unroll
            for (int j = 0; j < 8; ++j) v[t][j] += dpp_xor2(v[t][j + 8]);
            #pragma unroll
            for (int j = 0; j < 4; ++j) v[t][j] += dpp_xor1(v[t][j + 4]);
            #pragma unroll
            for (int j = 0; j < 2; ++j) v[t][j] += swz_xor4(v[t][j + 2]);
            v[t][0] += swz_xor8(v[t][1]);
            v[t][0] += swz_xor16(v[t][0]);
            v[t][0] += __shfl_xor(v[t][0], 32);
        }

        // score, argmin, blend, store
        #pragma unroll
        for (int t = 0; t < TB; ++t) {
            const float sc = cn_l - 2.0f * v[t][0];
            float m = sc;
            m = fminf(m, dpp_xor1(m));
            m = fminf(m, dpp_xor2(m));
            m = fminf(m, swz_xor4(m));
            m = fminf(m, swz_xor8(m));
            const unsigned long long mask = __ballot(sc == m);
            const int lmin = __builtin_ctzll(mask);
            const int bi = (((lmin >> 1) & 1) << 3) | ((lmin & 1) << 2)
                         | (((lmin >> 2) & 1) << 1) | ((lmin >> 3) & 1);
            const float4 c = lc4[(bi << 6) | lane];
            float4 o;
            o.x = alpha * xf[t].x + beta * c.x;
            o.y = alpha * xf[t].y + beta * c.y;
            o.z = alpha * xf[t].z + beta * c.z;
            o.w = alpha * xf[t].w + beta * c.w;
            out4[(size_t)(t0 + t) * (DFULL / 4) + h * 64 + lane] = o;
            if (lane == 0) atomicAdd(codef + t0 + t, (float)bi * kscale);
        }
    }
}

extern "C" void kernel_launch(void* const* d_in, const int* in_sizes, int n_in,
                              void* d_out, int out_size, void* d_ws, size_t ws_size,
                              hipStream_t stream) {
    const float* x      = (const float*)d_in[0];
    const float* cb     = (const float*)d_in[1];
    const float* alphap = (const float*)d_in[2];
    const int n_tokens  = in_sizes[0] / DFULL;            // 65536
    float* out   = (float*)d_out;
    float* codef = out + (size_t)n_tokens * DFULL;        // second output

    // code accumulated via fp32 atomicAdd across the 3 head-grids -> zero it
    hipMemsetAsync(codef, 0, (size_t)n_tokens * sizeof(float), stream);

    const int grid_x = 512;
    const int tok_per_block = n_tokens / grid_x;          // 128
    dim3 grid(grid_x, NH);
    rvq_head_kernel<<<grid, 256, 0, stream>>>(x, cb, alphap, out, codef,
                                              tok_per_block);
}